// Round 3
// baseline (121.453 us; speedup 1.0000x reference)
//
#include <hip/hip_runtime.h>
#include <hip/hip_bf16.h>
#include <stdint.h>

#define XLEN   262144
#define NT     513
#define NTP    528               // padded frames per batch (8*528 = 4224 = 33*128)
#define NB     8
#define NCOL   (NB * NTP)        // 4224 fused columns
#define NK     1088              // direct freq rows k = 0..1087
#define NFFT   2048
#define OUTKT  (2048 * NT)
#define BUFS   24576             // shorts per LDS buffer (48 KiB): 3 tiles of 128x64

typedef __attribute__((ext_vector_type(8))) short short8;
typedef __attribute__((ext_vector_type(4))) float f32x4;

__device__ __forceinline__ short cvt_bf16(float f) {
  return __builtin_bit_cast(short, (__bf16)f);
}

__device__ __forceinline__ void gload16(const short* g, const short* l) {
  __builtin_amdgcn_global_load_lds(
      (const __attribute__((address_space(1))) void*)g,
      (__attribute__((address_space(3))) void*)l, 16, 0, 0);
}

// ---------------- prep: fp32 weights (rows 0..1087) -> bf16 ----------------
__global__ __launch_bounds__(256) void conv_w_kernel(const float* __restrict__ wsin,
                                                     const float* __restrict__ wcos,
                                                     short* __restrict__ wc,
                                                     short* __restrict__ ws) {
  const int row = blockIdx.x;
  const int c = threadIdx.x * 8;
  const float* src = (blockIdx.y ? wsin : wcos) + (size_t)row * NFFT + c;
  short* dst = (blockIdx.y ? ws : wc) + (size_t)row * NFFT + c;
  f32x4 a = *(const f32x4*)src;
  f32x4 b = *(const f32x4*)(src + 4);
  short8 o;
#pragma unroll
  for (int j = 0; j < 4; ++j) { o[j] = cvt_bf16(a[j]); o[4 + j] = cvt_bf16(b[j]); }
  *(short8*)dst = o;
}

// ---------------- prep: reflect-padded frames -> bf16 [4224][2048] ----------------
__global__ __launch_bounds__(256) void conv_frames_kernel(const float* __restrict__ x,
                                                          short* __restrict__ fr) {
  const int j = blockIdx.x;
  const int b = j / NTP;
  const int t = j - b * NTP;
  const int c = threadIdx.x * 8;
  short8 o;
  if (t >= NT) {
#pragma unroll
    for (int k = 0; k < 8; ++k) o[k] = 0;
  } else {
    const float* xb = x + (size_t)b * XLEN;
    const int base = t * 512 + c - 1024;
    float v[8];
    if (base >= 0 && base + 7 < XLEN) {
      *(f32x4*)(v)     = *(const f32x4*)(xb + base);
      *(f32x4*)(v + 4) = *(const f32x4*)(xb + base + 4);
    } else {
#pragma unroll
      for (int k = 0; k < 8; ++k) {
        int m = base + k;
        m = (m < 0) ? -m : m;
        m = (m >= XLEN) ? (2 * XLEN - 2 - m) : m;
        v[k] = xb[m];
      }
    }
#pragma unroll
    for (int k = 0; k < 8; ++k) o[k] = cvt_bf16(v[k]);
  }
  *(short8*)&fr[(size_t)j * NFFT + c] = o;
}

// ---------------- main GEMM ----------------
// BM=128 (k), BN=128 (j), BK=64. 4 waves 2x2, each 64x64 per matrix (M=N=4).
// LDS buffer = [A_cos 128x64 | A_sin 128x64 | B_frames 128x64], rows of 64
// shorts (128 B); 16B-chunk XOR-swizzle with (row&7) applied on the global
// source (staging) and on the ds_read side. Double-buffered, prefetch 2-phase.
template <bool WS>
__global__ __launch_bounds__(256, 2) void dft_gemm_kernel(
    const float* __restrict__ x,
    const float* __restrict__ wsin_f,
    const float* __restrict__ wcos_f,
    const short* __restrict__ wc_bf,
    const short* __restrict__ ws_bf,
    const short* __restrict__ fr_bf,
    float* __restrict__ outR,
    float* __restrict__ outI) {
  __shared__ short lds[2 * BUFS];  // 96 KiB

  const int tid  = threadIdx.x;
  const int lane = tid & 63;
  const int wid  = tid >> 6;
  const int k0   = (blockIdx.x < 8) ? blockIdx.x * 128 : 960;  // overlap last tile
  const int kmin = (blockIdx.x == 8) ? 1024 : 0;               // skip dup rows
  const int j0   = blockIdx.y * 128;
  const int wr   = (wid >> 1) * 64;
  const int wcn  = (wid & 1) * 64;

  f32x4 accR[4][4], accI[4][4];
#pragma unroll
  for (int m = 0; m < 4; ++m)
#pragma unroll
    for (int n = 0; n < 4; ++n) { accR[m][n] = (f32x4)0.0f; accI[m][n] = (f32x4)0.0f; }

  const int fr_r = lane & 15;
  const int fk   = (lane >> 4) * 8;
  const int srow = lane >> 3;                  // 0..7 within an 8-row chunk
  const int scol = ((lane & 7) ^ srow) * 8;    // swizzled source chunk (shorts)

  // stage one 48 KiB buffer: 36 chunks of (8 rows x 64 shorts); 12 per wave
  auto stage = [&](int n0, int bb) {
#pragma unroll
    for (int i = 0; i < 12; ++i) {
      const int q   = wid * 12 + i;  // 0..47, wave-uniform
      const int reg = q >> 4;        // 0=wcos 1=wsin 2=frames
      const int rq  = q & 15;        // 8-row chunk within 128-row tile
      const int row = rq * 8 + srow;
      if (WS) {
        const short* src =
            (reg == 0) ? wc_bf + (size_t)(k0 + row) * NFFT + n0 + scol
          : (reg == 1) ? ws_bf + (size_t)(k0 + row) * NFFT + n0 + scol
                       : fr_bf + (size_t)(j0 + row) * NFFT + n0 + scol;
        gload16(src, &lds[bb + reg * 8192 + rq * 512]);
      } else {
        short8 v;
        if (reg < 2) {
          const float* s = (reg == 0 ? wcos_f : wsin_f) + (size_t)(k0 + row) * NFFT + n0 + scol;
          f32x4 u0 = *(const f32x4*)s, u1 = *(const f32x4*)(s + 4);
#pragma unroll
          for (int jx = 0; jx < 4; ++jx) { v[jx] = cvt_bf16(u0[jx]); v[4 + jx] = cvt_bf16(u1[jx]); }
        } else {
          const int jj = j0 + row;
          const int b = jj / NTP, t = jj - b * NTP;
          if (t < NT) {
            const float* xb = x + (size_t)b * XLEN;
            const int base = t * 512 + n0 + scol - 1024;
            float fv[8];
            if (base >= 0 && base + 7 < XLEN) {
              *(f32x4*)(fv)     = *(const f32x4*)(xb + base);
              *(f32x4*)(fv + 4) = *(const f32x4*)(xb + base + 4);
            } else {
#pragma unroll
              for (int k = 0; k < 8; ++k) {
                int m = base + k;
                m = (m < 0) ? -m : m;
                m = (m >= XLEN) ? (2 * XLEN - 2 - m) : m;
                fv[k] = xb[m];
              }
            }
#pragma unroll
            for (int k = 0; k < 8; ++k) v[k] = cvt_bf16(fv[k]);
          } else {
#pragma unroll
            for (int k = 0; k < 8; ++k) v[k] = 0;
          }
        }
        *(short8*)&lds[bb + reg * 8192 + rq * 512 + lane * 8] = v;
      }
    }
  };

  stage(0, 0);
  __syncthreads();

  for (int t = 0; t < 32; ++t) {
    const int bb = (t & 1) * BUFS;
    if (t < 31) stage((t + 1) * 64, bb ^ BUFS);  // prefetch next K-tile
    // ---- compute from bb: 2 substeps, 12 ds_read + 32 MFMA each ----
#pragma unroll
    for (int ks = 0; ks < 2; ++ks) {
      const int kb = ks * 32 + fk;
      short8 a_c[4], a_s[4], b_f[4];
#pragma unroll
      for (int m = 0; m < 4; ++m) {
        const int r = wr + m * 16 + fr_r;
        const int off = bb + (r << 6) + (((kb >> 3) ^ (r & 7)) << 3);
        a_c[m] = *(const short8*)&lds[off];
        a_s[m] = *(const short8*)&lds[8192 + off];
      }
#pragma unroll
      for (int n = 0; n < 4; ++n) {
        const int r = wcn + n * 16 + fr_r;
        const int off = bb + (r << 6) + (((kb >> 3) ^ (r & 7)) << 3);
        b_f[n] = *(const short8*)&lds[16384 + off];
      }
#pragma unroll
      for (int m = 0; m < 4; ++m)
#pragma unroll
        for (int n = 0; n < 4; ++n) {
          accR[m][n] = __builtin_amdgcn_mfma_f32_16x16x32_bf16(a_c[m], b_f[n], accR[m][n], 0, 0, 0);
          accI[m][n] = __builtin_amdgcn_mfma_f32_16x16x32_bf16(a_s[m], b_f[n], accI[m][n], 0, 0, 0);
        }
    }
    __syncthreads();  // drains vmcnt(0): next buffer staged; bb free to overwrite
  }

  // ---- epilogue: direct rows + Hermitian mirror (k in [1,960] -> 2048-k) ----
#pragma unroll
  for (int m = 0; m < 4; ++m) {
    const int k = k0 + wr + m * 16 + (lane >> 4) * 4;
    if (k < kmin) continue;
#pragma unroll
    for (int n = 0; n < 4; ++n) {
      const int j = j0 + wcn + n * 16 + (lane & 15);
      const int b = j / NTP;
      const int t = j - b * NTP;
      if (t < NT) {
        const size_t base = (size_t)b * OUTKT + (size_t)k * NT + t;
#pragma unroll
        for (int r = 0; r < 4; ++r) {
          const int kk = k + r;
          const float vr = accR[m][n][r];
          const float vi = accI[m][n][r];
          outR[base + (size_t)r * NT] = vr;
          outI[base + (size_t)r * NT] = -vi;
          if (kk >= 1 && kk <= 960) {
            const size_t mb = (size_t)b * OUTKT + (size_t)(2048 - kk) * NT + t;
            outR[mb] = vr;   // cos mirror: equal
            outI[mb] = vi;   // -(-imag): sin mirror negated
          }
        }
      }
    }
  }
}

extern "C" void kernel_launch(void* const* d_in, const int* in_sizes, int n_in,
                              void* d_out, int out_size, void* d_ws, size_t ws_size,
                              hipStream_t stream) {
  const float* x    = (const float*)d_in[0];
  const float* wsin = (const float*)d_in[1];
  const float* wcos = (const float*)d_in[2];
  float* outR = (float*)d_out;
  float* outI = outR + (size_t)NB * OUTKT;

  short* wc_bf = (short*)d_ws;
  short* ws_bf = wc_bf + (size_t)NK * NFFT;
  short* fr_bf = ws_bf + (size_t)NK * NFFT;
  const size_t ws_need = ((size_t)2 * NK + NCOL) * NFFT * sizeof(short);  // ~26.2 MB

  dim3 grid(9, NCOL / 128, 1);  // 9 x 33 = 297 blocks
  if (ws_size >= ws_need) {
    conv_w_kernel<<<dim3(NK, 2), 256, 0, stream>>>(wsin, wcos, wc_bf, ws_bf);
    conv_frames_kernel<<<NCOL, 256, 0, stream>>>(x, fr_bf);
    dft_gemm_kernel<true><<<grid, 256, 0, stream>>>(x, wsin, wcos, wc_bf, ws_bf, fr_bf, outR, outI);
  } else {
    dft_gemm_kernel<false><<<grid, 256, 0, stream>>>(x, wsin, wcos, wc_bf, ws_bf, fr_bf, outR, outI);
  }
}

// Round 4
// 77.830 us; speedup vs baseline: 1.5605x; 1.5605x over previous
//
#include <hip/hip_runtime.h>
#include <hip/hip_bf16.h>
#include <stdint.h>

#define XLEN   262144
#define NT     513
#define NTP    528               // padded frames per batch (8*528 = 4224 = 33*128)
#define NB     8
#define NCOL   (NB * NTP)        // 4224 fused columns
#define NK     1088              // direct freq rows k = 0..1087 (17 tiles of 64)
#define NFFT   2048
#define OUTKT  (2048 * NT)
#define NWG    561               // 17 * 33

typedef __attribute__((ext_vector_type(8))) short short8;
typedef __attribute__((ext_vector_type(4))) float f32x4;

__device__ __forceinline__ short cvt_bf16(float f) {
  return __builtin_bit_cast(short, (__bf16)f);
}

__device__ __forceinline__ void gload16(const short* g, const short* l) {
  __builtin_amdgcn_global_load_lds(
      (const __attribute__((address_space(1))) void*)g,
      (__attribute__((address_space(3))) void*)l, 16, 0, 0);
}

// ---------------- prep: fp32 weights (rows 0..1087) -> bf16 ----------------
__global__ __launch_bounds__(256) void conv_w_kernel(const float* __restrict__ wsin,
                                                     const float* __restrict__ wcos,
                                                     short* __restrict__ wc,
                                                     short* __restrict__ ws) {
  const int row = blockIdx.x;
  const int c = threadIdx.x * 8;
  const float* src = (blockIdx.y ? wsin : wcos) + (size_t)row * NFFT + c;
  short* dst = (blockIdx.y ? ws : wc) + (size_t)row * NFFT + c;
  f32x4 a = *(const f32x4*)src;
  f32x4 b = *(const f32x4*)(src + 4);
  short8 o;
#pragma unroll
  for (int j = 0; j < 4; ++j) { o[j] = cvt_bf16(a[j]); o[4 + j] = cvt_bf16(b[j]); }
  *(short8*)dst = o;
}

// ---------------- prep: reflect-padded frames -> bf16 [4224][2048] ----------------
__global__ __launch_bounds__(256) void conv_frames_kernel(const float* __restrict__ x,
                                                          short* __restrict__ fr) {
  const int j = blockIdx.x;
  const int b = j / NTP;
  const int t = j - b * NTP;
  const int c = threadIdx.x * 8;
  short8 o;
  if (t >= NT) {
#pragma unroll
    for (int k = 0; k < 8; ++k) o[k] = 0;
  } else {
    const float* xb = x + (size_t)b * XLEN;
    const int base = t * 512 + c - 1024;
    float v[8];
    if (base >= 0 && base + 7 < XLEN) {
      *(f32x4*)(v)     = *(const f32x4*)(xb + base);
      *(f32x4*)(v + 4) = *(const f32x4*)(xb + base + 4);
    } else {
#pragma unroll
      for (int k = 0; k < 8; ++k) {
        int m = base + k;
        m = (m < 0) ? -m : m;
        m = (m >= XLEN) ? (2 * XLEN - 2 - m) : m;
        v[k] = xb[m];
      }
    }
#pragma unroll
    for (int k = 0; k < 8; ++k) o[k] = cvt_bf16(v[k]);
  }
  *(short8*)&fr[(size_t)j * NFFT + c] = o;
}

// ---------------- main GEMM ----------------
// BM=64 (k), BN=128 (j), BK=64. 4 waves 2x2; each wave 32x64 per matrix
// (M=2, N=4): per 32-substep 8 ds_read_b128 : 16 MFMA (m97 ratio), B shared.
// LDS (single buffer, 32 KiB): [A_cos 64x64 | A_sin 64x64 | B 128x64] bf16,
// rows of 64 shorts; 16B-chunk XOR-swizzle with (row&7) applied to global
// source (staging; LDS written linearly by gload_lds) and to ds_read side.
// 3 blocks/CU co-resident -> cross-block overlap hides the barrier drain.
template <bool WS>
__global__ __launch_bounds__(256, 3) void dft_gemm_kernel(
    const float* __restrict__ x,
    const float* __restrict__ wsin_f,
    const float* __restrict__ wcos_f,
    const short* __restrict__ wc_bf,
    const short* __restrict__ ws_bf,
    const short* __restrict__ fr_bf,
    float* __restrict__ outR,
    float* __restrict__ outI) {
  __shared__ short lds[16384];  // 32 KiB

  const int tid  = threadIdx.x;
  const int lane = tid & 63;
  const int wid  = tid >> 6;

  // T1: bijective XCD swizzle (m204). nwg=561, q=70, r=1.
  const int o   = blockIdx.x;
  const int xcd = o & 7;
  const int wg  = ((xcd < 1) ? xcd * 71 : 71 + (xcd - 1) * 70) + (o >> 3);
  const int k0  = (wg % 17) * 64;
  const int j0  = (wg / 17) * 128;

  const int wrow = (wid >> 1) * 32;  // k-offset of this wave
  const int wcol = (wid & 1) * 64;   // j-offset of this wave

  f32x4 accR[2][4], accI[2][4];
#pragma unroll
  for (int m = 0; m < 2; ++m)
#pragma unroll
    for (int n = 0; n < 4; ++n) { accR[m][n] = (f32x4)0.0f; accI[m][n] = (f32x4)0.0f; }

  const int fr_r = lane & 15;
  const int fk   = (lane >> 4) * 8;
  const int srow = lane >> 3;                  // 0..7 within an 8-row chunk
  const int scol = ((lane & 7) ^ srow) * 8;    // swizzled source chunk (shorts)

  // one buffer = 32 chunks of (8 rows x 64 shorts); 8 per wave
  // q: 0..7 A_cos (64 rows), 8..15 A_sin, 16..31 B (128 rows)
  auto stage = [&](int n0) {
#pragma unroll
    for (int i = 0; i < 8; ++i) {
      const int q = wid * 8 + i;  // wave-uniform
      if (WS) {
        const short* src;
        int dst;
        if (q < 8) {
          src = wc_bf + (size_t)(k0 + q * 8 + srow) * NFFT + n0 + scol;
          dst = q * 512;
        } else if (q < 16) {
          src = ws_bf + (size_t)(k0 + (q - 8) * 8 + srow) * NFFT + n0 + scol;
          dst = 4096 + (q - 8) * 512;
        } else {
          src = fr_bf + (size_t)(j0 + (q - 16) * 8 + srow) * NFFT + n0 + scol;
          dst = 8192 + (q - 16) * 512;
        }
        gload16(src, &lds[dst]);
      } else {
        short8 v;
        int dst;
        if (q < 16) {
          const int row = (q & 7) * 8 + srow;
          const float* s = (q < 8 ? wcos_f : wsin_f) + (size_t)(k0 + row) * NFFT + n0 + scol;
          f32x4 u0 = *(const f32x4*)s, u1 = *(const f32x4*)(s + 4);
#pragma unroll
          for (int jx = 0; jx < 4; ++jx) { v[jx] = cvt_bf16(u0[jx]); v[4 + jx] = cvt_bf16(u1[jx]); }
          dst = (q < 8 ? 0 : 4096) + (q & 7) * 512 + lane * 8;
        } else {
          const int row = (q - 16) * 8 + srow;
          const int jj = j0 + row;
          const int b = jj / NTP, t = jj - b * NTP;
          if (t < NT) {
            const float* xb = x + (size_t)b * XLEN;
            const int base = t * 512 + n0 + scol - 1024;
            float fv[8];
            if (base >= 0 && base + 7 < XLEN) {
              *(f32x4*)(fv)     = *(const f32x4*)(xb + base);
              *(f32x4*)(fv + 4) = *(const f32x4*)(xb + base + 4);
            } else {
#pragma unroll
              for (int k = 0; k < 8; ++k) {
                int m = base + k;
                m = (m < 0) ? -m : m;
                m = (m >= XLEN) ? (2 * XLEN - 2 - m) : m;
                fv[k] = xb[m];
              }
            }
#pragma unroll
            for (int k = 0; k < 8; ++k) v[k] = cvt_bf16(fv[k]);
          } else {
#pragma unroll
            for (int k = 0; k < 8; ++k) v[k] = 0;
          }
          dst = 8192 + (q - 16) * 512 + lane * 8;
        }
        *(short8*)&lds[dst] = v;
      }
    }
  };

  for (int t = 0; t < 32; ++t) {
    if (t) __syncthreads();  // previous compute done; buffer free
    stage(t * 64);
    __syncthreads();         // staged data visible (vmcnt/lgkm drained)
#pragma unroll
    for (int ks = 0; ks < 2; ++ks) {
      const int kb = ks * 32 + fk;
      const int cc = kb >> 3;
      short8 a_c[2], a_s[2], b_f[4];
#pragma unroll
      for (int m = 0; m < 2; ++m) {
        const int r = wrow + m * 16 + fr_r;
        const int off = (r << 6) + ((cc ^ (r & 7)) << 3);
        a_c[m] = *(const short8*)&lds[off];
        a_s[m] = *(const short8*)&lds[4096 + off];
      }
#pragma unroll
      for (int n = 0; n < 4; ++n) {
        const int r = wcol + n * 16 + fr_r;
        const int off = (r << 6) + ((cc ^ (r & 7)) << 3);
        b_f[n] = *(const short8*)&lds[8192 + off];
      }
#pragma unroll
      for (int m = 0; m < 2; ++m)
#pragma unroll
        for (int n = 0; n < 4; ++n) {
          accR[m][n] = __builtin_amdgcn_mfma_f32_16x16x32_bf16(a_c[m], b_f[n], accR[m][n], 0, 0, 0);
          accI[m][n] = __builtin_amdgcn_mfma_f32_16x16x32_bf16(a_s[m], b_f[n], accI[m][n], 0, 0, 0);
        }
    }
  }

  // ---- epilogue: direct rows + Hermitian mirror (k in [1,960] -> 2048-k) ----
#pragma unroll
  for (int m = 0; m < 2; ++m) {
    const int k = k0 + wrow + m * 16 + (lane >> 4) * 4;
#pragma unroll
    for (int n = 0; n < 4; ++n) {
      const int j = j0 + wcol + n * 16 + (lane & 15);
      const int b = j / NTP;
      const int t = j - b * NTP;
      if (t < NT) {
        const size_t base = (size_t)b * OUTKT + (size_t)k * NT + t;
#pragma unroll
        for (int r = 0; r < 4; ++r) {
          const int kk = k + r;
          const float vr = accR[m][n][r];
          const float vi = accI[m][n][r];
          outR[base + (size_t)r * NT] = vr;
          outI[base + (size_t)r * NT] = -vi;
          if (kk >= 1 && kk <= 960) {
            const size_t mb = (size_t)b * OUTKT + (size_t)(2048 - kk) * NT + t;
            outR[mb] = vr;   // cos mirror: equal
            outI[mb] = vi;   // -(-imag): sin mirror negated
          }
        }
      }
    }
  }
}

extern "C" void kernel_launch(void* const* d_in, const int* in_sizes, int n_in,
                              void* d_out, int out_size, void* d_ws, size_t ws_size,
                              hipStream_t stream) {
  const float* x    = (const float*)d_in[0];
  const float* wsin = (const float*)d_in[1];
  const float* wcos = (const float*)d_in[2];
  float* outR = (float*)d_out;
  float* outI = outR + (size_t)NB * OUTKT;

  short* wc_bf = (short*)d_ws;
  short* ws_bf = wc_bf + (size_t)NK * NFFT;
  short* fr_bf = ws_bf + (size_t)NK * NFFT;
  const size_t ws_need = ((size_t)2 * NK + NCOL) * NFFT * sizeof(short);  // ~26.2 MB

  if (ws_size >= ws_need) {
    conv_w_kernel<<<dim3(NK, 2), 256, 0, stream>>>(wsin, wcos, wc_bf, ws_bf);
    conv_frames_kernel<<<NCOL, 256, 0, stream>>>(x, fr_bf);
    dft_gemm_kernel<true><<<NWG, 256, 0, stream>>>(x, wsin, wcos, wc_bf, ws_bf, fr_bf, outR, outI);
  } else {
    dft_gemm_kernel<false><<<NWG, 256, 0, stream>>>(x, wsin, wcos, wc_bf, ws_bf, fr_bf, outR, outI);
  }
}